// Round 6
// baseline (256.643 us; speedup 1.0000x reference)
//
#include <hip/hip_runtime.h>

#define TSEQ 2048
#define NB 4
#define NH 16
#define HD 64
#define CEMB 1024
#define MROWS (NB*TSEQ)   // 8192

typedef _Float16 half8 __attribute__((ext_vector_type(8)));
typedef _Float16 half4_t __attribute__((ext_vector_type(4)));
typedef float floatx4 __attribute__((ext_vector_type(4)));

__device__ __forceinline__ floatx4 mfma16x32(half8 a, half8 b, floatx4 c) {
    return __builtin_amdgcn_mfma_f32_16x16x32_f16(a, b, c, 0, 0, 0);
}

__device__ __forceinline__ void async16(const _Float16* g, _Float16* l) {
    __builtin_amdgcn_global_load_lds((const __attribute__((address_space(1))) void*)g,
                                     (__attribute__((address_space(3))) void*)l, 16, 0, 0);
}

// ---------------- fp32 -> fp16 convert (8 elem/thread) ----------------
__global__ __launch_bounds__(256) void cvt_fp32_fp16(const float* __restrict__ in,
                                                     _Float16* __restrict__ out) {
    size_t i = ((size_t)blockIdx.x * 256 + threadIdx.x) * 8;
    float4 a = *(const float4*)(in + i);
    float4 b = *(const float4*)(in + i + 4);
    half8 h;
    h[0] = (_Float16)a.x; h[1] = (_Float16)a.y; h[2] = (_Float16)a.z; h[3] = (_Float16)a.w;
    h[4] = (_Float16)b.x; h[5] = (_Float16)b.y; h[6] = (_Float16)b.z; h[7] = (_Float16)b.w;
    *(half8*)(out + i) = h;
}

// ------------- transpose + convert: in fp32 [R][Ccols] -> out fp16 [Ccols][R] -------------
__global__ __launch_bounds__(256) void transpose_cvt(const float* __restrict__ in,
                                                     _Float16* __restrict__ out,
                                                     int R, int Ccols) {
    __shared__ float tile[32][33];
    int bx = blockIdx.x;
    int by = blockIdx.y;
    int tx = threadIdx.x, ty = threadIdx.y;
    int x = bx * 32 + tx;
#pragma unroll
    for (int i = 0; i < 32; i += 8) {
        int y = by * 32 + ty + i;
        tile[ty + i][tx] = in[(size_t)y * Ccols + x];
    }
    __syncthreads();
#pragma unroll
    for (int i = 0; i < 32; i += 8) {
        int oc = bx * 32 + ty + i;
        int orow = by * 32 + tx;
        out[(size_t)oc * R + orow] = (_Float16)tile[tx][ty + i];
    }
}

// ---------------- NT GEMM: C[m][n] = sum_k A[m][k] * Bt[n][k] ----------------
// 256x128 block tile, 512 threads (8 waves, 4x2 wave grid of 64x64 tiles).
// Doubles MFMA-per-barrier vs 128x128 (latency-bound loop) at identical
// per-wave register cost. global_load_lds staging, XOR swizzle (period-2 rows).
template<int MODE>
__global__ __launch_bounds__(512, 4) void gemm_nt(const _Float16* __restrict__ A,
                                                  const _Float16* __restrict__ Bt,
                                                  float* __restrict__ Cf,
                                                  _Float16* __restrict__ Ch,
                                                  _Float16* __restrict__ VTh,
                                                  int N, int K) {
    __shared__ __align__(16) _Float16 As[2][8192];   // [256][32] halves, XOR swizzled
    __shared__ __align__(16) _Float16 Bs[2][4096];   // [128][32]

    const int tid = threadIdx.x;
    const int wv = tid >> 6, lane = tid & 63;
    const int wm = wv & 3, wn = wv >> 2;
    const int l16 = lane & 15, lq = lane >> 4;

    // L2 group swizzle (GROUP_M = 8 bm-rows per group)
    const int pid = blockIdx.x + gridDim.x * blockIdx.y;
    const int nn = gridDim.y;
    const int pig = 8 * nn;
    const int gid = pid / pig;
    const int rem = pid - gid * pig;
    const int bm = gid * 8 + (rem & 7);
    const int bn = rem >> 3;

    const int srow = lane >> 2;                                 // within-chunk row
    const int scol = ((lane & 3) ^ ((lane >> 3) & 3)) * 8;      // swizzled col (halves)
    const _Float16* Abase = A + (size_t)(bm * 256) * K;
    const _Float16* Bbase = Bt + (size_t)(bn * 128) * K;

    const floatx4 zero = {0.f, 0.f, 0.f, 0.f};
    floatx4 acc[4][4];
#pragma unroll
    for (int i = 0; i < 4; i++)
#pragma unroll
        for (int j = 0; j < 4; j++) acc[i][j] = zero;

    auto stage = [&](int bf, int k0) {
#pragma unroll
        for (int cc = 0; cc < 2; cc++) {           // A: 16 chunks, 2 per wave
            const int c = wv * 2 + cc;
            const size_t gofs = (size_t)(c * 16 + srow) * K + k0 + scol;
            async16(Abase + gofs, &As[bf][c * 512]);
        }
        {                                          // B: 8 chunks, 1 per wave
            const int c = wv;
            const size_t gofs = (size_t)(c * 16 + srow) * K + k0 + scol;
            async16(Bbase + gofs, &Bs[bf][c * 512]);
        }
    };

    stage(0, 0);
    int buf = 0;
    const int sw = (lq ^ ((l16 >> 1) & 3)) * 8;   // read-side swizzle (halves)
    for (int k0 = 0; k0 < K; k0 += 32) {
        __syncthreads();                 // implicit vmcnt(0): buf staged, buf^1 free
        if (k0 + 32 < K) stage(buf ^ 1, k0 + 32);
        half8 af[4], bf[4];
#pragma unroll
        for (int i = 0; i < 4; i++) {
            af[i] = *(const half8*)&As[buf][(wm * 64 + i * 16 + l16) * 32 + sw];
            bf[i] = *(const half8*)&Bs[buf][(wn * 64 + i * 16 + l16) * 32 + sw];
        }
#pragma unroll
        for (int i = 0; i < 4; i++)
#pragma unroll
            for (int j = 0; j < 4; j++)
                acc[i][j] = mfma16x32(af[i], bf[j], acc[i][j]);
        buf ^= 1;
    }

    if (MODE == 1) {
#pragma unroll
        for (int i = 0; i < 4; i++) {
            int row = bm * 256 + wm * 64 + i * 16 + lq * 4;
#pragma unroll
            for (int j = 0; j < 4; j++) {
                int col = bn * 128 + wn * 64 + j * 16 + l16;
#pragma unroll
                for (int r = 0; r < 4; r++)
                    Cf[(size_t)(row + r) * N + col] = acc[i][j][r];
            }
        }
    } else {
        const int which = bn >> 3;   // block-uniform (n>>10)
        if (which < 2) {
#pragma unroll
            for (int j = 0; j < 4; j++) {
                int n = bn * 128 + wn * 64 + j * 16 + l16;
                int c = n & 1023, h = c >> 6, d = c & 63;
                _Float16* dst = Ch + (size_t)which * ((size_t)MROWS * CEMB)
                                   + (size_t)h * (TSEQ * HD) + d;
#pragma unroll
                for (int i = 0; i < 4; i++) {
                    int row = bm * 256 + wm * 64 + i * 16 + lq * 4;
#pragma unroll
                    for (int r = 0; r < 4; r++) {
                        int m = row + r;
                        int b = m >> 11, t = m & 2047;
                        dst[(size_t)b * (NH * TSEQ * HD) + (size_t)t * HD] = (_Float16)acc[i][j][r];
                    }
                }
            }
        } else {
            // V^T: [bh][d][t], 4 consecutive t -> packed b64 store
#pragma unroll
            for (int j = 0; j < 4; j++) {
                int n = bn * 128 + wn * 64 + j * 16 + l16;
                int c = n & 1023, h = c >> 6, d = c & 63;
#pragma unroll
                for (int i = 0; i < 4; i++) {
                    int m0 = bm * 256 + wm * 64 + i * 16 + lq * 4;
                    int b = m0 >> 11, t = m0 & 2047;
                    half4_t pk;
#pragma unroll
                    for (int r = 0; r < 4; r++) pk[r] = (_Float16)acc[i][j][r];
                    *(half4_t*)&VTh[(((size_t)(b * NH + h)) * HD + d) * TSEQ + t] = pk;
                }
            }
        }
    }
}

// ---------------- flash attention, S^T formulation, max-free softmax ----------------
// Grid (16, 64): 1024 blocks, 4/CU. Round-robin dispatch puts blocks id,
// id+256, id+512, id+768 on one CU: same xq, b = 0,1,2,3. The b-indexed qt
// permutation makes each CU's resident qt set sum to a constant 30 tile-units.
__global__ __launch_bounds__(256, 4) void attn_fwd(const _Float16* __restrict__ Qg,
                                                   const _Float16* __restrict__ Kg,
                                                   const _Float16* __restrict__ VTg,
                                                   _Float16* __restrict__ Y) {
    __shared__ __align__(16) _Float16 Ks[2][4096];   // [64 keys][64 d], swizzled
    __shared__ __align__(16) _Float16 Vt[2][4096];   // [64 d][64 keys], swizzled

    const int tid = threadIdx.x;
    const int w = tid >> 6, lane = tid & 63;
    const int l16 = lane & 15, quad = lane >> 4;
    const int bh = blockIdx.y;
    const int xq = blockIdx.x;   // 0..15
    const int b = bh >> 4, h = bh & 15;
    const int qt = (b == 0) ? xq
                 : (b == 1) ? (15 - xq)
                 : (b == 2) ? ((xq + 8) & 15)
                            : ((7 - xq) & 15);

    const _Float16* Qb = Qg + (size_t)bh * TSEQ * HD;
    const _Float16* Kb = Kg + (size_t)bh * TSEQ * HD;
    const _Float16* Vb = VTg + (size_t)bh * HD * TSEQ;

    const _Float16 ksc = (_Float16)(0.125f * 1.44269504089f);  // 1/sqrt(64)*log2(e)
    const floatx4 zero = {0.f, 0.f, 0.f, 0.f};

    half8 qf[2][2];
#pragma unroll
    for (int g = 0; g < 2; g++) {
        const _Float16* qrow = Qb + (size_t)(qt * 128 + g * 64 + w * 16 + l16) * HD;
        qf[g][0] = *(const half8*)(qrow + quad * 8);
        qf[g][1] = *(const half8*)(qrow + 32 + quad * 8);
#pragma unroll
        for (int e = 0; e < 8; e++) { qf[g][0][e] *= ksc; qf[g][1][e] *= ksc; }
    }

    floatx4 o[2][4];
#pragma unroll
    for (int g = 0; g < 2; g++)
#pragma unroll
        for (int dt = 0; dt < 4; dt++) o[g][dt] = zero;
    float lsum[2] = {0.f, 0.f};

    const int srow8 = lane >> 3;
    const int scol8 = ((lane & 7) ^ (lane >> 3)) * 8;   // XOR-8 swizzled col (halves)

    auto stage = [&](int bf, int kt2) {
#pragma unroll
        for (int cc = 0; cc < 2; cc++) {
            const int c = w * 2 + cc;
            const int row = c * 8 + srow8;
            async16(Kb + (size_t)(kt2 * 64 + row) * HD + scol8, &Ks[bf][c * 512]);
            async16(Vb + (size_t)row * TSEQ + kt2 * 64 + scol8, &Vt[bf][c * 512]);
        }
    };

    const int kmax = 2 * qt + 1;
    stage(0, 0);
    int buf = 0;
    for (int kt = 0; kt <= kmax; ++kt) {
        __syncthreads();                   // buf staged (vmcnt drain), buf^1 free
        if (kt < kmax) stage(buf ^ 1, kt + 1);

        // K fragments (shared by both q-groups)
        half8 kf0[4], kf1[4];
#pragma unroll
        for (int nj = 0; nj < 4; nj++) {
            const int rb = (nj * 16 + l16) * 64;
            kf0[nj] = *(const half8*)&Ks[buf][rb + ((quad ^ (l16 & 7)) * 8)];
            kf1[nj] = *(const half8*)&Ks[buf][rb + (((quad ^ 4) ^ (l16 & 7)) * 8)];
        }

        const bool doA = (kt <= 2 * qt);
        half8 pf[2][2];
#pragma unroll
        for (int g = 0; g < 2; g++) {
            if (g == 0 && !doA) continue;  // wave-uniform skip (last tile is g=1 only)
            floatx4 st[4];
#pragma unroll
            for (int nj = 0; nj < 4; nj++) {
                floatx4 t = mfma16x32(kf0[nj], qf[g][0], zero);
                st[nj] = mfma16x32(kf1[nj], qf[g][1], t);
            }
            if (kt * 64 + 63 > qt * 128 + g * 64 + w * 16) {   // boundary tiles only
                const int klim = qt * 128 + g * 64 + w * 16 + l16 - kt * 64;
#pragma unroll
                for (int nj = 0; nj < 4; nj++)
#pragma unroll
                    for (int r = 0; r < 4; r++) {
                        int key = nj * 16 + quad * 4 + r;
                        if (key > klim) st[nj][r] = -1e30f;   // exp2 -> 0
                    }
            }
#pragma unroll
            for (int nj = 0; nj < 4; nj++)
#pragma unroll
                for (int r = 0; r < 4; r++) {
                    float p = __builtin_amdgcn_exp2f(st[nj][r]);
                    lsum[g] += p;
                    pf[g][nj >> 1][(nj & 1) * 4 + r] = (_Float16)p;
                }
        }

        // O += P*V, paired 16x16x32; V-fragments shared across groups
#pragma unroll
        for (int u = 0; u < 2; u++) {
#pragma unroll
            for (int dt = 0; dt < 4; dt++) {
                const int rb = (dt * 16 + l16) * 64;
                const int g0 = u * 4 + (quad >> 1);
                const int sub = (quad & 1) * 4;
                half4_t lo = *(const half4_t*)&Vt[buf][rb + ((g0 ^ (l16 & 7)) * 8 + sub)];
                half4_t hi = *(const half4_t*)&Vt[buf][rb + (((g0 + 2) ^ (l16 & 7)) * 8 + sub)];
                half8 vf;
                vf[0] = lo[0]; vf[1] = lo[1]; vf[2] = lo[2]; vf[3] = lo[3];
                vf[4] = hi[0]; vf[5] = hi[1]; vf[6] = hi[2]; vf[7] = hi[3];
                if (doA) o[0][dt] = mfma16x32(pf[0][u], vf, o[0][dt]);
                o[1][dt] = mfma16x32(pf[1][u], vf, o[1][dt]);
            }
        }
        buf ^= 1;
    }

#pragma unroll
    for (int g = 0; g < 2; g++) {
        float lt = lsum[g];
        lt += __shfl_xor(lt, 16);
        lt += __shfl_xor(lt, 32);      // lt = full l for query w*16+l16 (this group)
        float linv[4];
#pragma unroll
        for (int r = 0; r < 4; r++) linv[r] = 1.0f / __shfl(lt, quad * 4 + r);
#pragma unroll
        for (int dt = 0; dt < 4; dt++)
#pragma unroll
            for (int r = 0; r < 4; r++) {
                int q = qt * 128 + g * 64 + w * 16 + quad * 4 + r;
                int d = dt * 16 + l16;
                Y[((size_t)(b * TSEQ + q)) * CEMB + h * HD + d] = (_Float16)(o[g][dt][r] * linv[r]);
            }
    }
}

extern "C" void kernel_launch(void* const* d_in, const int* in_sizes, int n_in,
                              void* d_out, int out_size, void* d_ws, size_t ws_size,
                              hipStream_t stream) {
    const float* x0     = (const float*)d_in[0];
    const float* w_attn = (const float*)d_in[1];
    const float* w_proj = (const float*)d_in[2];
    float* out = (float*)d_out;

    _Float16* xh  = (_Float16*)d_ws;                       // [8192][1024]
    _Float16* wqt = xh  + (size_t)MROWS * CEMB;            // [3072][1024] (w_attn^T)
    _Float16* wpt = wqt + (size_t)3 * CEMB * CEMB;         // [1024][1024] (w_proj^T)
    _Float16* qh  = wpt + (size_t)CEMB * CEMB;             // Q [bh][t][d]
    _Float16* kh  = qh  + (size_t)MROWS * CEMB;            // K [bh][t][d]
    _Float16* vt  = kh  + (size_t)MROWS * CEMB;            // V^T [bh][d][t]
    _Float16* yh  = vt  + (size_t)MROWS * CEMB;            // [8192][1024]

    cvt_fp32_fp16<<<(MROWS * CEMB) / (256 * 8), 256, 0, stream>>>(x0, xh);
    transpose_cvt<<<dim3(3 * CEMB / 32, CEMB / 32), dim3(32, 8), 0, stream>>>(w_attn, wqt, CEMB, 3 * CEMB);
    transpose_cvt<<<dim3(CEMB / 32, CEMB / 32), dim3(32, 8), 0, stream>>>(w_proj, wpt, CEMB, CEMB);

    gemm_nt<0><<<dim3(MROWS / 256, 3 * CEMB / 128), 512, 0, stream>>>(xh, wqt, nullptr, qh, vt, 3 * CEMB, CEMB);
    attn_fwd<<<dim3(TSEQ / 128, NB * NH), 256, 0, stream>>>(qh, kh, vt, yh);
    gemm_nt<1><<<dim3(MROWS / 256, CEMB / 128), 512, 0, stream>>>(yh, wpt, out, nullptr, nullptr, CEMB, CEMB);
}

// Round 7
// 249.050 us; speedup vs baseline: 1.0305x; 1.0305x over previous
//
#include <hip/hip_runtime.h>

#define TSEQ 2048
#define NB 4
#define NH 16
#define HD 64
#define CEMB 1024
#define MROWS (NB*TSEQ)   // 8192

typedef _Float16 half8 __attribute__((ext_vector_type(8)));
typedef _Float16 half4_t __attribute__((ext_vector_type(4)));
typedef float floatx4 __attribute__((ext_vector_type(4)));

__device__ __forceinline__ floatx4 mfma16x32(half8 a, half8 b, floatx4 c) {
    return __builtin_amdgcn_mfma_f32_16x16x32_f16(a, b, c, 0, 0, 0);
}

__device__ __forceinline__ void async16(const _Float16* g, _Float16* l) {
    __builtin_amdgcn_global_load_lds((const __attribute__((address_space(1))) void*)g,
                                     (__attribute__((address_space(3))) void*)l, 16, 0, 0);
}

// ---------------- fp32 -> fp16 convert (8 elem/thread) ----------------
__global__ __launch_bounds__(256) void cvt_fp32_fp16(const float* __restrict__ in,
                                                     _Float16* __restrict__ out) {
    size_t i = ((size_t)blockIdx.x * 256 + threadIdx.x) * 8;
    float4 a = *(const float4*)(in + i);
    float4 b = *(const float4*)(in + i + 4);
    half8 h;
    h[0] = (_Float16)a.x; h[1] = (_Float16)a.y; h[2] = (_Float16)a.z; h[3] = (_Float16)a.w;
    h[4] = (_Float16)b.x; h[5] = (_Float16)b.y; h[6] = (_Float16)b.z; h[7] = (_Float16)b.w;
    *(half8*)(out + i) = h;
}

// ------------- transpose + convert: in fp32 [R][Ccols] -> out fp16 [Ccols][R] -------------
__global__ __launch_bounds__(256) void transpose_cvt(const float* __restrict__ in,
                                                     _Float16* __restrict__ out,
                                                     int R, int Ccols) {
    __shared__ float tile[32][33];
    int bx = blockIdx.x;
    int by = blockIdx.y;
    int tx = threadIdx.x, ty = threadIdx.y;
    int x = bx * 32 + tx;
#pragma unroll
    for (int i = 0; i < 32; i += 8) {
        int y = by * 32 + ty + i;
        tile[ty + i][tx] = in[(size_t)y * Ccols + x];
    }
    __syncthreads();
#pragma unroll
    for (int i = 0; i < 32; i += 8) {
        int oc = bx * 32 + ty + i;
        int orow = by * 32 + tx;
        out[(size_t)oc * R + orow] = (_Float16)tile[tx][ty + i];
    }
}

// ---------------- NT GEMM: C[m][n] = sum_k A[m][k] * Bt[n][k] ----------------
// Templated tile-M: BM=256 (512 thr, 8 waves 4x2) or BM=128 (256 thr, 4 waves 2x2).
// global_load_lds staging, XOR swizzle (period-2 rows), GROUP_M=8 L2 swizzle.
template<int MODE, int BM>
__global__ __launch_bounds__(BM * 2, 4) void gemm_nt(const _Float16* __restrict__ A,
                                                     const _Float16* __restrict__ Bt,
                                                     float* __restrict__ Cf,
                                                     _Float16* __restrict__ Ch,
                                                     _Float16* __restrict__ VTh,
                                                     int N, int K) {
    __shared__ __align__(16) _Float16 As[2][BM * 32];
    __shared__ __align__(16) _Float16 Bs[2][4096];

    const int tid = threadIdx.x;
    const int wv = tid >> 6, lane = tid & 63;
    const int wm = (BM == 256) ? (wv & 3) : (wv >> 1);
    const int wn = (BM == 256) ? (wv >> 2) : (wv & 1);
    const int l16 = lane & 15, lq = lane >> 4;

    // L2 group swizzle (GROUP_M = 8 bm-rows per group)
    const int pid = blockIdx.x + gridDim.x * blockIdx.y;
    const int nn = gridDim.y;
    const int pig = 8 * nn;
    const int gid = pid / pig;
    const int rem = pid - gid * pig;
    const int bm = gid * 8 + (rem & 7);
    const int bn = rem >> 3;

    const int srow = lane >> 2;                                 // within-chunk row
    const int scol = ((lane & 3) ^ ((lane >> 3) & 3)) * 8;      // swizzled col (halves)
    const _Float16* Abase = A + (size_t)(bm * BM) * K;
    const _Float16* Bbase = Bt + (size_t)(bn * 128) * K;

    const floatx4 zero = {0.f, 0.f, 0.f, 0.f};
    floatx4 acc[4][4];
#pragma unroll
    for (int i = 0; i < 4; i++)
#pragma unroll
        for (int j = 0; j < 4; j++) acc[i][j] = zero;

    auto stage = [&](int bf, int k0) {
#pragma unroll
        for (int cc = 0; cc < 2; cc++) {           // A: BM/16 chunks, 2 per wave
            const int c = wv * 2 + cc;
            const size_t gofs = (size_t)(c * 16 + srow) * K + k0 + scol;
            async16(Abase + gofs, &As[bf][c * 512]);
        }
        if (BM == 256) {                           // B: 8 chunks, 1 per wave
            const int c = wv;
            const size_t gofs = (size_t)(c * 16 + srow) * K + k0 + scol;
            async16(Bbase + gofs, &Bs[bf][c * 512]);
        } else {                                   // B: 8 chunks, 2 per wave
#pragma unroll
            for (int cc = 0; cc < 2; cc++) {
                const int c = wv * 2 + cc;
                const size_t gofs = (size_t)(c * 16 + srow) * K + k0 + scol;
                async16(Bbase + gofs, &Bs[bf][c * 512]);
            }
        }
    };

    stage(0, 0);
    int buf = 0;
    const int sw = (lq ^ ((l16 >> 1) & 3)) * 8;   // read-side swizzle (halves)
    for (int k0 = 0; k0 < K; k0 += 32) {
        __syncthreads();                 // implicit vmcnt(0): buf staged, buf^1 free
        if (k0 + 32 < K) stage(buf ^ 1, k0 + 32);
        half8 af[4], bf[4];
#pragma unroll
        for (int i = 0; i < 4; i++) {
            af[i] = *(const half8*)&As[buf][(wm * 64 + i * 16 + l16) * 32 + sw];
            bf[i] = *(const half8*)&Bs[buf][(wn * 64 + i * 16 + l16) * 32 + sw];
        }
#pragma unroll
        for (int i = 0; i < 4; i++)
#pragma unroll
            for (int j = 0; j < 4; j++)
                acc[i][j] = mfma16x32(af[i], bf[j], acc[i][j]);
        buf ^= 1;
    }

    if (MODE == 1) {
#pragma unroll
        for (int i = 0; i < 4; i++) {
            int row = bm * BM + wm * 64 + i * 16 + lq * 4;
#pragma unroll
            for (int j = 0; j < 4; j++) {
                int col = bn * 128 + wn * 64 + j * 16 + l16;
#pragma unroll
                for (int r = 0; r < 4; r++)
                    Cf[(size_t)(row + r) * N + col] = acc[i][j][r];
            }
        }
    } else {
        const int which = bn >> 3;   // block-uniform (n>>10)
        if (which < 2) {
#pragma unroll
            for (int j = 0; j < 4; j++) {
                int n = bn * 128 + wn * 64 + j * 16 + l16;
                int c = n & 1023, h = c >> 6, d = c & 63;
                _Float16* dst = Ch + (size_t)which * ((size_t)MROWS * CEMB)
                                   + (size_t)h * (TSEQ * HD) + d;
#pragma unroll
                for (int i = 0; i < 4; i++) {
                    int row = bm * BM + wm * 64 + i * 16 + lq * 4;
#pragma unroll
                    for (int r = 0; r < 4; r++) {
                        int m = row + r;
                        int b = m >> 11, t = m & 2047;
                        dst[(size_t)b * (NH * TSEQ * HD) + (size_t)t * HD] = (_Float16)acc[i][j][r];
                    }
                }
            }
        } else {
            // V^T: [bh][d][t], 4 consecutive t -> packed b64 store
#pragma unroll
            for (int j = 0; j < 4; j++) {
                int n = bn * 128 + wn * 64 + j * 16 + l16;
                int c = n & 1023, h = c >> 6, d = c & 63;
#pragma unroll
                for (int i = 0; i < 4; i++) {
                    int m0 = bm * BM + wm * 64 + i * 16 + lq * 4;
                    int b = m0 >> 11, t = m0 & 2047;
                    half4_t pk;
#pragma unroll
                    for (int r = 0; r < 4; r++) pk[r] = (_Float16)acc[i][j][r];
                    *(half4_t*)&VTh[(((size_t)(b * NH + h)) * HD + d) * TSEQ + t] = pk;
                }
            }
        }
    }
}

// ---------------- flash attention: 256 q / block, 512 threads, 8 waves ----------------
// Each staged 64-key K/V tile serves 256 queries -> staging traffic and barrier
// count per FLOP halved vs 128-q blocks. S^T formulation, max-free softmax.
// Grid (8,64) = 512 blocks = 2/CU; qt = (b<2 ? x : 7-x) balances co-resident pair.
__global__ __launch_bounds__(512, 4) void attn_fwd(const _Float16* __restrict__ Qg,
                                                   const _Float16* __restrict__ Kg,
                                                   const _Float16* __restrict__ VTg,
                                                   _Float16* __restrict__ Y) {
    __shared__ __align__(16) _Float16 Ks[2][4096];   // [64 keys][64 d], swizzled
    __shared__ __align__(16) _Float16 Vt[2][4096];   // [64 d][64 keys], swizzled

    const int tid = threadIdx.x;
    const int w = tid >> 6, lane = tid & 63;
    const int l16 = lane & 15, quad = lane >> 4;
    const int bh = blockIdx.y;
    const int x = blockIdx.x;    // 0..7
    const int b = bh >> 4, h = bh & 15;
    const int qt = (b < 2) ? x : (7 - x);

    const _Float16* Qb = Qg + (size_t)bh * TSEQ * HD;
    const _Float16* Kb = Kg + (size_t)bh * TSEQ * HD;
    const _Float16* Vb = VTg + (size_t)bh * HD * TSEQ;

    const _Float16 ksc = (_Float16)(0.125f * 1.44269504089f);  // 1/sqrt(64)*log2(e)
    const floatx4 zero = {0.f, 0.f, 0.f, 0.f};

    half8 qf[2][2];
#pragma unroll
    for (int g = 0; g < 2; g++) {
        const _Float16* qrow = Qb + (size_t)(qt * 256 + g * 128 + w * 16 + l16) * HD;
        qf[g][0] = *(const half8*)(qrow + quad * 8);
        qf[g][1] = *(const half8*)(qrow + 32 + quad * 8);
#pragma unroll
        for (int e = 0; e < 8; e++) { qf[g][0][e] *= ksc; qf[g][1][e] *= ksc; }
    }

    floatx4 o[2][4];
#pragma unroll
    for (int g = 0; g < 2; g++)
#pragma unroll
        for (int dt = 0; dt < 4; dt++) o[g][dt] = zero;
    float lsum[2] = {0.f, 0.f};

    const int srow8 = lane >> 3;
    const int scol8 = ((lane & 7) ^ (lane >> 3)) * 8;   // XOR-8 swizzled col (halves)

    auto stage = [&](int bf, int kt2) {
        const int row = w * 8 + srow8;                  // 8 waves -> 1 chunk each
        async16(Kb + (size_t)(kt2 * 64 + row) * HD + scol8, &Ks[bf][w * 512]);
        async16(Vb + (size_t)row * TSEQ + kt2 * 64 + scol8, &Vt[bf][w * 512]);
    };

    const int kmax = 4 * qt + 3;
    stage(0, 0);
    int buf = 0;
    for (int kt = 0; kt <= kmax; ++kt) {
        __syncthreads();                   // buf staged (vmcnt drain), buf^1 free
        if (kt < kmax) stage(buf ^ 1, kt + 1);

        // K fragments (shared by both q-groups)
        half8 kf0[4], kf1[4];
#pragma unroll
        for (int nj = 0; nj < 4; nj++) {
            const int rb = (nj * 16 + l16) * 64;
            kf0[nj] = *(const half8*)&Ks[buf][rb + ((quad ^ (l16 & 7)) * 8)];
            kf1[nj] = *(const half8*)&Ks[buf][rb + (((quad ^ 4) ^ (l16 & 7)) * 8)];
        }

        const bool doA = (kt <= 4 * qt + 1);   // g=0 needs tiles up to 4qt+1
        half8 pf[2][2];
#pragma unroll
        for (int g = 0; g < 2; g++) {
            if (g == 0 && !doA) continue;  // wave-uniform skip (last 2 tiles g=1 only)
            floatx4 st[4];
#pragma unroll
            for (int nj = 0; nj < 4; nj++) {
                floatx4 t = mfma16x32(kf0[nj], qf[g][0], zero);
                st[nj] = mfma16x32(kf1[nj], qf[g][1], t);
            }
            if (kt * 64 + 63 > qt * 256 + g * 128 + w * 16) {   // boundary tiles only
                const int klim = qt * 256 + g * 128 + w * 16 + l16 - kt * 64;
#pragma unroll
                for (int nj = 0; nj < 4; nj++)
#pragma unroll
                    for (int r = 0; r < 4; r++) {
                        int key = nj * 16 + quad * 4 + r;
                        if (key > klim) st[nj][r] = -1e30f;   // exp2 -> 0
                    }
            }
#pragma unroll
            for (int nj = 0; nj < 4; nj++)
#pragma unroll
                for (int r = 0; r < 4; r++) {
                    float p = __builtin_amdgcn_exp2f(st[nj][r]);
                    lsum[g] += p;
                    pf[g][nj >> 1][(nj & 1) * 4 + r] = (_Float16)p;
                }
        }

        // O += P*V, paired 16x16x32; V-fragments shared across groups
#pragma unroll
        for (int u = 0; u < 2; u++) {
#pragma unroll
            for (int dt = 0; dt < 4; dt++) {
                const int rb = (dt * 16 + l16) * 64;
                const int g0 = u * 4 + (quad >> 1);
                const int sub = (quad & 1) * 4;
                half4_t lo = *(const half4_t*)&Vt[buf][rb + ((g0 ^ (l16 & 7)) * 8 + sub)];
                half4_t hi = *(const half4_t*)&Vt[buf][rb + (((g0 + 2) ^ (l16 & 7)) * 8 + sub)];
                half8 vf;
                vf[0] = lo[0]; vf[1] = lo[1]; vf[2] = lo[2]; vf[3] = lo[3];
                vf[4] = hi[0]; vf[5] = hi[1]; vf[6] = hi[2]; vf[7] = hi[3];
                if (doA) o[0][dt] = mfma16x32(pf[0][u], vf, o[0][dt]);
                o[1][dt] = mfma16x32(pf[1][u], vf, o[1][dt]);
            }
        }
        buf ^= 1;
    }

#pragma unroll
    for (int g = 0; g < 2; g++) {
        float lt = lsum[g];
        lt += __shfl_xor(lt, 16);
        lt += __shfl_xor(lt, 32);      // lt = full l for query w*16+l16 (this group)
        float linv[4];
#pragma unroll
        for (int r = 0; r < 4; r++) linv[r] = 1.0f / __shfl(lt, quad * 4 + r);
#pragma unroll
        for (int dt = 0; dt < 4; dt++)
#pragma unroll
            for (int r = 0; r < 4; r++) {
                int q = qt * 256 + g * 128 + w * 16 + quad * 4 + r;
                int d = dt * 16 + l16;
                Y[((size_t)(b * TSEQ + q)) * CEMB + h * HD + d] = (_Float16)(o[g][dt][r] * linv[r]);
            }
    }
}

extern "C" void kernel_launch(void* const* d_in, const int* in_sizes, int n_in,
                              void* d_out, int out_size, void* d_ws, size_t ws_size,
                              hipStream_t stream) {
    const float* x0     = (const float*)d_in[0];
    const float* w_attn = (const float*)d_in[1];
    const float* w_proj = (const float*)d_in[2];
    float* out = (float*)d_out;

    _Float16* xh  = (_Float16*)d_ws;                       // [8192][1024]
    _Float16* wqt = xh  + (size_t)MROWS * CEMB;            // [3072][1024] (w_attn^T)
    _Float16* wpt = wqt + (size_t)3 * CEMB * CEMB;         // [1024][1024] (w_proj^T)
    _Float16* qh  = wpt + (size_t)CEMB * CEMB;             // Q [bh][t][d]
    _Float16* kh  = qh  + (size_t)MROWS * CEMB;            // K [bh][t][d]
    _Float16* vt  = kh  + (size_t)MROWS * CEMB;            // V^T [bh][d][t]
    _Float16* yh  = vt  + (size_t)MROWS * CEMB;            // [8192][1024]

    cvt_fp32_fp16<<<(MROWS * CEMB) / (256 * 8), 256, 0, stream>>>(x0, xh);
    transpose_cvt<<<dim3(3 * CEMB / 32, CEMB / 32), dim3(32, 8), 0, stream>>>(w_attn, wqt, CEMB, 3 * CEMB);
    transpose_cvt<<<dim3(CEMB / 32, CEMB / 32), dim3(32, 8), 0, stream>>>(w_proj, wpt, CEMB, CEMB);

    gemm_nt<0, 256><<<dim3(MROWS / 256, 3 * CEMB / 128), 512, 0, stream>>>(xh, wqt, nullptr, qh, vt, 3 * CEMB, CEMB);
    attn_fwd<<<dim3(TSEQ / 256, NB * NH), 512, 0, stream>>>(qh, kh, vt, yh);
    gemm_nt<1, 128><<<dim3(MROWS / 128, CEMB / 128), 256, 0, stream>>>(yh, wpt, out, nullptr, nullptr, CEMB, CEMB);
}